// Round 9
// baseline (60.628 us; speedup 1.0000x reference)
//
#include <hip/hip_runtime.h>

#define NGT 30000
#define GT_TILE 1024
#define NBLK_G 30            // ceil(30000/1024)
#define PRANGE 128           // preds per block
#define NCHUNK 27            // m0: 2, m1: 5, m2: 20 chunks of 128
#define RB 128               // reduce blocks

// ---------------------------------------------------------------------------
// Two-phase chamfer, LDS-pipe-tuned (R8 post-mortem: ds_read_b128 pipe
// occupancy ~22us/CU was the co-limiter at 1 read / 2-4 pairs).
// grid = (NBLK_G, NCHUNK), block = 256. LDS: sgt[1024] + spred[128] (18 KB).
// Phase 1: 4 gt pts/thread in regs; one broadcast ds_read_b128 per pred
//          serves 4 pairs -> atomicMin gtmin (d = (p2-2dot) + g2 after min).
// Phase 2: 8-lane groups own 8 preds in regs (1 read / 8 pairs); groups
//          0-15 scan gt rows 0-511, groups 16-31 rows 512-1023 (halves
//          combine via the same atomicMin); lane s reads sgt[k*8+s]
//          (8 distinct 16B addrs/wave -> banks 0..31, conflict-free);
//          3-level shfl_xor -> atomicMin predmin.
// Per-lane arrays stay small & statically indexed (R5-R7: pm[32]+ spills).
// atomicMin on int bits of non-negative floats: exact, order-independent,
// deterministic; init 0x7f7f7f7f (huge positive).
// ---------------------------------------------------------------------------
__global__ __launch_bounds__(256) void chamfer_kernel(
    const float* __restrict__ gt,
    const float* __restrict__ pbd0,
    const float* __restrict__ pbd1,
    const float* __restrict__ pbd2,
    float* __restrict__ gtmin,     // [3*NGT] pre-init 0x7f
    float* __restrict__ predmin)   // [3240]  pre-init 0x7f
{
    __shared__ float4 sgt[GT_TILE];
    __shared__ float4 spred[PRANGE];

    const int tid = threadIdx.x;
    const int c = blockIdx.y;

    int mesh, cidx;
    if (c < 2)      { mesh = 0; cidx = c; }
    else if (c < 7) { mesh = 1; cidx = c - 2; }
    else            { mesh = 2; cidx = c - 7; }
    const int coff = cidx * PRANGE;
    const int n    = (mesh == 0) ? 156 : (mesh == 1) ? 618 : 2466;
    const int poff = (mesh == 0) ? 0   : (mesh == 1) ? 156 : 774;
    const float* pred = (mesh == 0) ? pbd0 : (mesh == 1) ? pbd1 : pbd2;
    const int np = min(PRANGE, n - coff);

    if (tid < PRANGE) {
        float4 v = make_float4(0.f, 0.f, 0.f, 3.0e38f);   // sentinel pred
        if (tid < np) {
            const int j = coff + tid;
            float px = pred[3*j], py = pred[3*j+1], pz = pred[3*j+2];
            v = make_float4(px, py, pz, px*px + py*py + pz*pz);
        }
        spred[tid] = v;
    }

    const int gbase = blockIdx.x * GT_TILE;
    float gx[4], gy[4], gz[4], g2[4], gmin[4];
    #pragma unroll
    for (int k = 0; k < 4; ++k) {
        const int g = gbase + k * 256 + tid;
        float x = 1e18f, y = 1e18f, z = 1e18f;   // sentinel gt: huge, finite
        if (g < NGT) { x = gt[3*g]; y = gt[3*g+1]; z = gt[3*g+2]; }
        gx[k] = x; gy[k] = y; gz[k] = z;
        g2[k] = x*x + y*y + z*z;
        gmin[k] = 3.0e38f;
        sgt[k * 256 + tid] = make_float4(x, y, z, g2[k]);
    }
    __syncthreads();

    // ---- phase 1: gt-side min, 4 pairs per broadcast ds_read ----
    #pragma unroll 4
    for (int j = 0; j < PRANGE; ++j) {
        const float4 p = spred[j];                 // broadcast ds_read_b128
        #pragma unroll
        for (int k = 0; k < 4; ++k) {
            float dot = gx[k]*p.x + gy[k]*p.y + gz[k]*p.z;
            float t = __fmaf_rn(dot, -2.0f, p.w);  // p2 - 2*dot
            gmin[k] = fminf(gmin[k], t);
        }
    }
    #pragma unroll
    for (int k = 0; k < 4; ++k) {
        const int g = gbase + k * 256 + tid;
        if (g < NGT)
            atomicMin((int*)(gtmin + mesh * NGT + g),
                      __float_as_int(gmin[k] + g2[k]));
    }

    // ---- phase 2: pred-side min; 8-lane groups x 8 preds, half-tile scan ----
    {
        const int grp  = tid >> 3;                 // 0..31
        const int s    = tid & 7;                  // interleaved slice
        const int pset = (grp & 15) * 8;           // pred group base
        const int half = (grp >> 4) * 512;         // gt half-tile base
        float4 p[8];
        #pragma unroll
        for (int r = 0; r < 8; ++r) p[r] = spred[pset + r];
        float mn[8];
        #pragma unroll
        for (int r = 0; r < 8; ++r) mn[r] = 3.0e38f;
        #pragma unroll 2
        for (int k = 0; k < 512 / 8; ++k) {
            const float4 q = sgt[half + k * 8 + s];  // 8 addrs -> banks 0..31
            #pragma unroll
            for (int r = 0; r < 8; ++r) {
                float dot = q.x*p[r].x + q.y*p[r].y + q.z*p[r].z;
                float t = __fmaf_rn(dot, -2.0f, q.w);  // g2 - 2*dot
                mn[r] = fminf(mn[r], t);
            }
        }
        #pragma unroll
        for (int off = 1; off < 8; off <<= 1) {
            #pragma unroll
            for (int r = 0; r < 8; ++r)
                mn[r] = fminf(mn[r], __shfl_xor(mn[r], off, 64));
        }
        if (s == 0) {
            #pragma unroll
            for (int r = 0; r < 8; ++r) {
                const int pj = pset + r;
                if (pj < np)
                    atomicMin((int*)(predmin + poff + coff + pj),
                              __float_as_int(mn[r] + p[r].w));
            }
        }
    }
}

// ---------------------------------------------------------------------------
// Partial reduce: gtmin/predmin sums + edge + laplace, RB blocks x 256.
// Deterministic: fixed index slices, fixed-order block tree reduce.
// ---------------------------------------------------------------------------
__global__ __launch_bounds__(256) void partial_kernel(
    const float* __restrict__ pc0, const float* __restrict__ pc1, const float* __restrict__ pc2,
    const float* __restrict__ pbd0, const float* __restrict__ pbd1, const float* __restrict__ pbd2,
    const int* __restrict__ ed0, const int* __restrict__ ed1, const int* __restrict__ ed2,
    const int* __restrict__ li0, const int* __restrict__ li1, const int* __restrict__ li2,
    const float* __restrict__ gtmin, const float* __restrict__ predmin,
    float* __restrict__ partials)   // [RB*4]
{
    const int   NVs[3]   = {156, 618, 2466};
    const int   NEs[3]   = {462, 1848, 7392};
    const int   poffs[3] = {0, 156, 774};
    const int   eoffs[3] = {0, 462, 2310};
    const float lapc[3]  = {0.2f, 1.0f, 1.0f};
    const float* pcs[3]  = {pc0, pc1, pc2};
    const float* pbds[3] = {pbd0, pbd1, pbd2};
    const int*   eds[3]  = {ed0, ed1, ed2};
    const int*   lis[3]  = {li0, li1, li2};

    const int tid = threadIdx.x;
    const int stride = gridDim.x * 256;
    float ch = 0.f, ed = 0.f, lp = 0.f;

    // index space: [0,90000) gtmin | [90000,93240) predmin |
    //              [93240,102942) edges | [102942,106182) laplace verts
    for (int idx = blockIdx.x * 256 + tid; idx < 106182; idx += stride) {
        if (idx < 90000) {
            ch += gtmin[idx] * (1.0f / 30000.0f);
        } else if (idx < 93240) {
            int p = idx - 90000;
            int m = (p < 156) ? 0 : (p < 774) ? 1 : 2;
            ch += predmin[p] * (1.0f / (float)NVs[m]);
        } else if (idx < 102942) {
            int e = idx - 93240;
            int m = (e < 462) ? 0 : (e < 2310) ? 1 : 2;
            int el = e - eoffs[m];
            const int* E = eds[m];
            const float* P = pcs[m];
            int a = E[2*el], b = E[2*el+1];
            float dx = P[3*a]   - P[3*b];
            float dy = P[3*a+1] - P[3*b+1];
            float dz = P[3*a+2] - P[3*b+2];
            ed += (dx*dx + dy*dy + dz*dz) * (300.0f / (float)NEs[m]);
        } else {
            int v = idx - 102942;
            int m = (v < 156) ? 0 : (v < 774) ? 1 : 2;
            int vl = v - poffs[m];
            const int* L = lis[m];
            const float* PB = pbds[m];
            const float* PC = pcs[m];
            float mvx = PB[3*vl]   - PC[3*vl];
            float mvy = PB[3*vl+1] - PC[3*vl+1];
            float mvz = PB[3*vl+2] - PC[3*vl+2];
            float sx = 0.f, sy = 0.f, sz = 0.f;
            #pragma unroll
            for (int k = 0; k < 8; ++k) {
                int nb = L[10*vl + k];
                if (nb >= 0) {
                    sx += PB[3*nb]   - PC[3*nb];
                    sy += PB[3*nb+1] - PC[3*nb+1];
                    sz += PB[3*nb+2] - PC[3*nb+2];
                }
            }
            float invdeg = 1.0f / (float)L[10*vl + 9];
            float dx = mvx - sx * invdeg;
            float dy = mvy - sy * invdeg;
            float dz = mvz - sz * invdeg;
            float t = dx*dx + dy*dy + dz*dz;
            if (m > 0) t += mvx*mvx + mvy*mvy + mvz*mvz;
            lp += t * (lapc[m] / (float)NVs[m]);
        }
    }

    __shared__ float sred[12];
    for (int off = 32; off; off >>= 1) {
        ch += __shfl_down(ch, off, 64);
        ed += __shfl_down(ed, off, 64);
        lp += __shfl_down(lp, off, 64);
    }
    const int lane = tid & 63, wid = tid >> 6;
    if (lane == 0) { sred[wid] = ch; sred[4 + wid] = ed; sred[8 + wid] = lp; }
    __syncthreads();
    if (tid == 0) {
        partials[blockIdx.x * 4 + 0] = sred[0] + sred[1] + sred[2] + sred[3];
        partials[blockIdx.x * 4 + 1] = sred[4] + sred[5] + sred[6] + sred[7];
        partials[blockIdx.x * 4 + 2] = sred[8] + sred[9] + sred[10] + sred[11];
    }
}

// ---------------------------------------------------------------------------
// Final: sum RB partials, write 4 outputs. 1 block x 128.
// ---------------------------------------------------------------------------
__global__ __launch_bounds__(128) void final_kernel(
    const float* __restrict__ partials, float* __restrict__ out)
{
    const int tid = threadIdx.x;
    float ch = partials[4*tid], ed = partials[4*tid+1], lp = partials[4*tid+2];
    __shared__ float s[6];
    for (int off = 32; off; off >>= 1) {
        ch += __shfl_down(ch, off, 64);
        ed += __shfl_down(ed, off, 64);
        lp += __shfl_down(lp, off, 64);
    }
    if ((tid & 63) == 0) {
        int w = tid >> 6;
        s[w] = ch; s[2 + w] = ed; s[4 + w] = lp;
    }
    __syncthreads();
    if (tid == 0) {
        float c = s[0] + s[1], e = s[2] + s[3], l = s[4] + s[5];
        out[0] = 100.0f * c + 0.1f * e + 0.3f * l;
        out[1] = c;
        out[2] = e;
        out[3] = l;
    }
}

extern "C" void kernel_launch(void* const* d_in, const int* in_sizes, int n_in,
                              void* d_out, int out_size, void* d_ws, size_t ws_size,
                              hipStream_t stream) {
    const float* gt   = (const float*)d_in[0];
    const float* pc0  = (const float*)d_in[1];
    const float* pbd0 = (const float*)d_in[2];
    const int*   ed0  = (const int*)  d_in[3];
    const int*   li0  = (const int*)  d_in[4];
    const float* pc1  = (const float*)d_in[5];
    const float* pbd1 = (const float*)d_in[6];
    const int*   ed1  = (const int*)  d_in[7];
    const int*   li1  = (const int*)  d_in[8];
    const float* pc2  = (const float*)d_in[9];
    const float* pbd2 = (const float*)d_in[10];
    const int*   ed2  = (const int*)  d_in[11];
    const int*   li2  = (const int*)  d_in[12];

    float* ws       = (float*)d_ws;
    float* gtmin    = ws;                    // 3*NGT floats
    float* predmin  = ws + 3 * NGT;          // 3240 floats
    float* partials = ws + 3 * NGT + 3240;   // RB*4 floats
    float* out      = (float*)d_out;

    hipMemsetAsync(gtmin, 0x7f, (3 * NGT + 3240) * sizeof(float), stream);

    dim3 grid(NBLK_G, NCHUNK);
    chamfer_kernel<<<grid, 256, 0, stream>>>(gt, pbd0, pbd1, pbd2, gtmin, predmin);

    partial_kernel<<<RB, 256, 0, stream>>>(pc0, pc1, pc2, pbd0, pbd1, pbd2,
                                           ed0, ed1, ed2, li0, li1, li2,
                                           gtmin, predmin, partials);

    final_kernel<<<1, 128, 0, stream>>>(partials, out);
}

// Round 10
// 50.737 us; speedup vs baseline: 1.1950x; 1.1950x over previous
//
#include <hip/hip_runtime.h>

#define NGT 30000
#define GT_TILE 512
#define NBLK_G 59            // ceil(30000/512)
#define PRANGE 128           // preds per block
#define NCHUNK 27            // m0: 2, m1: 5, m2: 20 chunks of 128
#define NPACK 3456           // 27 * 128 chunk-padded pred slots
#define RB 128               // reduce blocks

// ---------------------------------------------------------------------------
// Pack kernel: predpack[i] = {x,y,z,norm} for chunk-padded pred slots;
// sentinel slots get w=3e38 (never win a min). Layout: m0 slots [0,256),
// m1 [256,896), m2 [896,3456).
// ---------------------------------------------------------------------------
__global__ __launch_bounds__(256) void pack_kernel(
    const float* __restrict__ pbd0,
    const float* __restrict__ pbd1,
    const float* __restrict__ pbd2,
    float4* __restrict__ predpack)
{
    const int i = blockIdx.x * 256 + threadIdx.x;
    if (i >= NPACK) return;
    int mesh, j, n;
    if (i < 256)      { mesh = 0; j = i;       n = 156; }
    else if (i < 896) { mesh = 1; j = i - 256; n = 618; }
    else              { mesh = 2; j = i - 896; n = 2466; }
    const float* p = (mesh == 0) ? pbd0 : (mesh == 1) ? pbd1 : pbd2;
    float4 v = make_float4(0.f, 0.f, 0.f, 3.0e38f);
    if (j < n) {
        float x = p[3*j], y = p[3*j+1], z = p[3*j+2];
        v = make_float4(x, y, z, x*x + y*y + z*z);
    }
    predpack[i] = v;
}

// ---------------------------------------------------------------------------
// Two-phase chamfer (R8 structure = best measured; R9 taught that halving
// LDS reads at the cost of half the grid LOSES — keep 59x27=1593 blocks).
// New in R10: phase 1 reads preds via wave-uniform s_load_dwordx4 from
// predpack (SGPR operands) instead of LDS broadcast -> removes 128 of 192
// per-wave ds_read_b128 (the R8 LDS-pipe co-limiter), no TLP cost.
// Phase 1: 2 gt pts/thread in regs; per pred j (uniform scalar load),
//          d=(p2-2dot), gt-side running min -> atomicMin gtmin (+g2 after).
// Phase 2: 8-lane groups own 4 preds in regs; lane s scans interleaved
//          slice sgt[k*8+s] (8 distinct 16B addrs/wave -> 32 banks,
//          conflict-free); 3-level shfl_xor -> atomicMin predmin (+p2).
// atomicMin on int bits of non-negative floats: exact, order-independent,
// deterministic; init 0x7f7f7f7f. Sentinel gt = 1e18 coords (finite).
// ---------------------------------------------------------------------------
__global__ __launch_bounds__(256) void chamfer_kernel(
    const float* __restrict__ gt,
    const float4* __restrict__ predpack,
    float* __restrict__ gtmin,     // [3*NGT] pre-init 0x7f
    float* __restrict__ predmin)   // [3240]  pre-init 0x7f
{
    __shared__ float4 sgt[GT_TILE];
    __shared__ float4 spred[PRANGE];

    const int tid = threadIdx.x;
    const int c = blockIdx.y;

    int mesh, cidx;
    if (c < 2)      { mesh = 0; cidx = c; }
    else if (c < 7) { mesh = 1; cidx = c - 2; }
    else            { mesh = 2; cidx = c - 7; }
    const int coff = cidx * PRANGE;
    const int n    = (mesh == 0) ? 156 : (mesh == 1) ? 618 : 2466;
    const int poff = (mesh == 0) ? 0   : (mesh == 1) ? 156 : 774;
    const int pbase = ((mesh == 0) ? 0 : (mesh == 1) ? 256 : 896) + coff;
    const int np = min(PRANGE, n - coff);

    if (tid < PRANGE) spred[tid] = predpack[pbase + tid];

    const int gbase = blockIdx.x * GT_TILE;
    float gx[2], gy[2], gz[2], g2[2], gmin[2];
    #pragma unroll
    for (int k = 0; k < 2; ++k) {
        const int g = gbase + k * 256 + tid;
        float x = 1e18f, y = 1e18f, z = 1e18f;   // sentinel gt: huge, finite
        if (g < NGT) { x = gt[3*g]; y = gt[3*g+1]; z = gt[3*g+2]; }
        gx[k] = x; gy[k] = y; gz[k] = z;
        g2[k] = x*x + y*y + z*z;
        gmin[k] = 3.0e38f;
        sgt[k * 256 + tid] = make_float4(x, y, z, g2[k]);
    }
    __syncthreads();

    // ---- phase 1: gt-side min; preds via uniform s_load_dwordx4 ----
    {
        const float4* __restrict__ pp = predpack + pbase;  // uniform base
        #pragma unroll 8
        for (int j = 0; j < PRANGE; ++j) {
            const float4 p = pp[j];                // uniform -> SMEM load
            #pragma unroll
            for (int k = 0; k < 2; ++k) {
                float dot = gx[k]*p.x + gy[k]*p.y + gz[k]*p.z;
                float t = __fmaf_rn(dot, -2.0f, p.w);  // p2 - 2*dot
                gmin[k] = fminf(gmin[k], t);
            }
        }
    }
    #pragma unroll
    for (int k = 0; k < 2; ++k) {
        const int g = gbase + k * 256 + tid;
        if (g < NGT)
            atomicMin((int*)(gtmin + mesh * NGT + g),
                      __float_as_int(gmin[k] + g2[k]));
    }

    // ---- phase 2: pred-side min; 8-lane groups x 4 preds in regs ----
    {
        const int grp = tid >> 3;                  // 0..31 -> preds 4g..4g+3
        const int s   = tid & 7;                   // interleaved slice
        float4 p[4];
        #pragma unroll
        for (int r = 0; r < 4; ++r) p[r] = spred[4*grp + r];
        float mn[4] = {3.0e38f, 3.0e38f, 3.0e38f, 3.0e38f};
        #pragma unroll 4
        for (int k = 0; k < GT_TILE / 8; ++k) {
            const float4 q = sgt[k * 8 + s];       // 8 addrs -> banks 0..31
            #pragma unroll
            for (int r = 0; r < 4; ++r) {
                float dot = q.x*p[r].x + q.y*p[r].y + q.z*p[r].z;
                float t = __fmaf_rn(dot, -2.0f, q.w);  // g2 - 2*dot
                mn[r] = fminf(mn[r], t);
            }
        }
        #pragma unroll
        for (int off = 1; off < 8; off <<= 1) {
            #pragma unroll
            for (int r = 0; r < 4; ++r)
                mn[r] = fminf(mn[r], __shfl_xor(mn[r], off, 64));
        }
        if (s == 0) {
            #pragma unroll
            for (int r = 0; r < 4; ++r) {
                const int pj = 4*grp + r;
                if (pj < np)
                    atomicMin((int*)(predmin + poff + coff + pj),
                              __float_as_int(mn[r] + p[r].w));
            }
        }
    }
}

// ---------------------------------------------------------------------------
// Partial reduce: gtmin/predmin sums + edge + laplace, RB blocks x 256.
// Deterministic: fixed index slices, fixed-order block tree reduce.
// ---------------------------------------------------------------------------
__global__ __launch_bounds__(256) void partial_kernel(
    const float* __restrict__ pc0, const float* __restrict__ pc1, const float* __restrict__ pc2,
    const float* __restrict__ pbd0, const float* __restrict__ pbd1, const float* __restrict__ pbd2,
    const int* __restrict__ ed0, const int* __restrict__ ed1, const int* __restrict__ ed2,
    const int* __restrict__ li0, const int* __restrict__ li1, const int* __restrict__ li2,
    const float* __restrict__ gtmin, const float* __restrict__ predmin,
    float* __restrict__ partials)   // [RB*4]
{
    const int   NVs[3]   = {156, 618, 2466};
    const int   NEs[3]   = {462, 1848, 7392};
    const int   poffs[3] = {0, 156, 774};
    const int   eoffs[3] = {0, 462, 2310};
    const float lapc[3]  = {0.2f, 1.0f, 1.0f};
    const float* pcs[3]  = {pc0, pc1, pc2};
    const float* pbds[3] = {pbd0, pbd1, pbd2};
    const int*   eds[3]  = {ed0, ed1, ed2};
    const int*   lis[3]  = {li0, li1, li2};

    const int tid = threadIdx.x;
    const int stride = gridDim.x * 256;
    float ch = 0.f, ed = 0.f, lp = 0.f;

    // index space: [0,90000) gtmin | [90000,93240) predmin |
    //              [93240,102942) edges | [102942,106182) laplace verts
    for (int idx = blockIdx.x * 256 + tid; idx < 106182; idx += stride) {
        if (idx < 90000) {
            ch += gtmin[idx] * (1.0f / 30000.0f);
        } else if (idx < 93240) {
            int p = idx - 90000;
            int m = (p < 156) ? 0 : (p < 774) ? 1 : 2;
            ch += predmin[p] * (1.0f / (float)NVs[m]);
        } else if (idx < 102942) {
            int e = idx - 93240;
            int m = (e < 462) ? 0 : (e < 2310) ? 1 : 2;
            int el = e - eoffs[m];
            const int* E = eds[m];
            const float* P = pcs[m];
            int a = E[2*el], b = E[2*el+1];
            float dx = P[3*a]   - P[3*b];
            float dy = P[3*a+1] - P[3*b+1];
            float dz = P[3*a+2] - P[3*b+2];
            ed += (dx*dx + dy*dy + dz*dz) * (300.0f / (float)NEs[m]);
        } else {
            int v = idx - 102942;
            int m = (v < 156) ? 0 : (v < 774) ? 1 : 2;
            int vl = v - poffs[m];
            const int* L = lis[m];
            const float* PB = pbds[m];
            const float* PC = pcs[m];
            float mvx = PB[3*vl]   - PC[3*vl];
            float mvy = PB[3*vl+1] - PC[3*vl+1];
            float mvz = PB[3*vl+2] - PC[3*vl+2];
            float sx = 0.f, sy = 0.f, sz = 0.f;
            #pragma unroll
            for (int k = 0; k < 8; ++k) {
                int nb = L[10*vl + k];
                if (nb >= 0) {
                    sx += PB[3*nb]   - PC[3*nb];
                    sy += PB[3*nb+1] - PC[3*nb+1];
                    sz += PB[3*nb+2] - PC[3*nb+2];
                }
            }
            float invdeg = 1.0f / (float)L[10*vl + 9];
            float dx = mvx - sx * invdeg;
            float dy = mvy - sy * invdeg;
            float dz = mvz - sz * invdeg;
            float t = dx*dx + dy*dy + dz*dz;
            if (m > 0) t += mvx*mvx + mvy*mvy + mvz*mvz;
            lp += t * (lapc[m] / (float)NVs[m]);
        }
    }

    __shared__ float sred[12];
    for (int off = 32; off; off >>= 1) {
        ch += __shfl_down(ch, off, 64);
        ed += __shfl_down(ed, off, 64);
        lp += __shfl_down(lp, off, 64);
    }
    const int lane = tid & 63, wid = tid >> 6;
    if (lane == 0) { sred[wid] = ch; sred[4 + wid] = ed; sred[8 + wid] = lp; }
    __syncthreads();
    if (tid == 0) {
        partials[blockIdx.x * 4 + 0] = sred[0] + sred[1] + sred[2] + sred[3];
        partials[blockIdx.x * 4 + 1] = sred[4] + sred[5] + sred[6] + sred[7];
        partials[blockIdx.x * 4 + 2] = sred[8] + sred[9] + sred[10] + sred[11];
    }
}

// ---------------------------------------------------------------------------
// Final: sum RB partials, write 4 outputs. 1 block x 128.
// ---------------------------------------------------------------------------
__global__ __launch_bounds__(128) void final_kernel(
    const float* __restrict__ partials, float* __restrict__ out)
{
    const int tid = threadIdx.x;
    float ch = partials[4*tid], ed = partials[4*tid+1], lp = partials[4*tid+2];
    __shared__ float s[6];
    for (int off = 32; off; off >>= 1) {
        ch += __shfl_down(ch, off, 64);
        ed += __shfl_down(ed, off, 64);
        lp += __shfl_down(lp, off, 64);
    }
    if ((tid & 63) == 0) {
        int w = tid >> 6;
        s[w] = ch; s[2 + w] = ed; s[4 + w] = lp;
    }
    __syncthreads();
    if (tid == 0) {
        float c = s[0] + s[1], e = s[2] + s[3], l = s[4] + s[5];
        out[0] = 100.0f * c + 0.1f * e + 0.3f * l;
        out[1] = c;
        out[2] = e;
        out[3] = l;
    }
}

extern "C" void kernel_launch(void* const* d_in, const int* in_sizes, int n_in,
                              void* d_out, int out_size, void* d_ws, size_t ws_size,
                              hipStream_t stream) {
    const float* gt   = (const float*)d_in[0];
    const float* pc0  = (const float*)d_in[1];
    const float* pbd0 = (const float*)d_in[2];
    const int*   ed0  = (const int*)  d_in[3];
    const int*   li0  = (const int*)  d_in[4];
    const float* pc1  = (const float*)d_in[5];
    const float* pbd1 = (const float*)d_in[6];
    const int*   ed1  = (const int*)  d_in[7];
    const int*   li1  = (const int*)  d_in[8];
    const float* pc2  = (const float*)d_in[9];
    const float* pbd2 = (const float*)d_in[10];
    const int*   ed2  = (const int*)  d_in[11];
    const int*   li2  = (const int*)  d_in[12];

    float* ws       = (float*)d_ws;
    float* gtmin    = ws;                    // 3*NGT floats
    float* predmin  = ws + 3 * NGT;          // 3240 floats
    float* partials = ws + 3 * NGT + 3240;   // RB*4 floats
    float4* predpack = (float4*)(ws + 3 * NGT + 3240 + RB * 4 + 4);
    // align predpack to 16B
    predpack = (float4*)(((uintptr_t)predpack + 15) & ~(uintptr_t)15);
    float* out      = (float*)d_out;

    hipMemsetAsync(gtmin, 0x7f, (3 * NGT + 3240) * sizeof(float), stream);

    pack_kernel<<<(NPACK + 255) / 256, 256, 0, stream>>>(pbd0, pbd1, pbd2, predpack);

    dim3 grid(NBLK_G, NCHUNK);
    chamfer_kernel<<<grid, 256, 0, stream>>>(gt, predpack, gtmin, predmin);

    partial_kernel<<<RB, 256, 0, stream>>>(pc0, pc1, pc2, pbd0, pbd1, pbd2,
                                           ed0, ed1, ed2, li0, li1, li2,
                                           gtmin, predmin, partials);

    final_kernel<<<1, 128, 0, stream>>>(partials, out);
}

// Round 11
// 44.918 us; speedup vs baseline: 1.3497x; 1.1295x over previous
//
#include <hip/hip_runtime.h>

#define NGT 30000
#define GT_TILE 512
#define NBLK_G 59            // ceil(30000/512)
#define PRANGE 128           // preds per block
#define NCHUNK 27            // m0: 2, m1: 5, m2: 20 chunks of 128
#define NPACK 3456           // 27 * 128 chunk-padded pred slots
#define RB 128               // reduce blocks

typedef float v2f __attribute__((ext_vector_type(2)));

// ws layout (float offsets). predpack first (16B aligned at ws base).
#define OFF_PREDPACK 0              // 3456 float4 = 13824 floats
#define OFF_GTPART   13824          // 27 * 30000 = 810000
#define OFF_PREDMIN  823824         // 3240
#define OFF_PARTIALS 827064         // RB*4 = 512
#define OFF_COUNTER  827576         // 1 uint

// ---------------------------------------------------------------------------
// Pack kernel: predpack[i] = {x,y,z,norm} (sentinel w=3e38 for pad slots);
// also inits predmin[3240] to huge and zeroes the done-counter (replaces the
// memset dispatch). Layout: m0 slots [0,256), m1 [256,896), m2 [896,3456).
// ---------------------------------------------------------------------------
__global__ __launch_bounds__(256) void pack_kernel(
    const float* __restrict__ pbd0,
    const float* __restrict__ pbd1,
    const float* __restrict__ pbd2,
    float4* __restrict__ predpack,
    float* __restrict__ predmin,
    unsigned* __restrict__ counter)
{
    const int i = blockIdx.x * 256 + threadIdx.x;
    if (i == 0) *counter = 0u;
    if (i < 3240) predmin[i] = __int_as_float(0x7f7f7f7f);
    if (i >= NPACK) return;
    int mesh, j, n;
    if (i < 256)      { mesh = 0; j = i;       n = 156; }
    else if (i < 896) { mesh = 1; j = i - 256; n = 618; }
    else              { mesh = 2; j = i - 896; n = 2466; }
    const float* p = (mesh == 0) ? pbd0 : (mesh == 1) ? pbd1 : pbd2;
    float4 v = make_float4(0.f, 0.f, 0.f, 3.0e38f);
    if (j < n) {
        float x = p[3*j], y = p[3*j+1], z = p[3*j+2];
        v = make_float4(x, y, z, x*x + y*y + z*z);
    }
    predpack[i] = v;
}

// ---------------------------------------------------------------------------
// Two-phase chamfer (R8 grid: 59x27=1593 blocks — TLP is king), packed-f32.
// Phase 1: 2 gt pts/thread as a v2f; preds via wave-uniform s_load from
//          predpack; v_pk_mul/fma -> ~3 instr/pair. Result written as a
//          plain per-chunk store to gtpart[c][g] (no atomic, no init).
// Phase 2: 8-lane groups own 4 preds (component-packed as v2f pairs);
//          lane s scans interleaved slice sgt[k*8+s] (8 distinct 16B
//          addrs/wave -> 32 banks, conflict-free); 3-level shfl_xor
//          -> atomicMin predmin (int bits, non-negative, deterministic).
// ---------------------------------------------------------------------------
__global__ __launch_bounds__(256) void chamfer_kernel(
    const float* __restrict__ gt,
    const float4* __restrict__ predpack,
    float* __restrict__ gtpart,    // [NCHUNK * NGT], write-only
    float* __restrict__ predmin)   // [3240], pre-init by pack_kernel
{
    __shared__ float4 sgt[GT_TILE];
    __shared__ float4 spred[PRANGE];

    const int tid = threadIdx.x;
    const int c = blockIdx.y;

    int mesh, cidx;
    if (c < 2)      { mesh = 0; cidx = c; }
    else if (c < 7) { mesh = 1; cidx = c - 2; }
    else            { mesh = 2; cidx = c - 7; }
    const int coff = cidx * PRANGE;
    const int n    = (mesh == 0) ? 156 : (mesh == 1) ? 618 : 2466;
    const int poff = (mesh == 0) ? 0   : (mesh == 1) ? 156 : 774;
    const int pbase = ((mesh == 0) ? 0 : (mesh == 1) ? 256 : 896) + coff;
    const int np = min(PRANGE, n - coff);

    if (tid < PRANGE) spred[tid] = predpack[pbase + tid];

    const int gbase = blockIdx.x * GT_TILE;
    float gx[2], gy[2], gz[2], g2[2];
    #pragma unroll
    for (int k = 0; k < 2; ++k) {
        const int g = gbase + k * 256 + tid;
        float x = 1e18f, y = 1e18f, z = 1e18f;   // sentinel gt: huge, finite
        if (g < NGT) { x = gt[3*g]; y = gt[3*g+1]; z = gt[3*g+2]; }
        gx[k] = x; gy[k] = y; gz[k] = z;
        g2[k] = x*x + y*y + z*z;
        sgt[k * 256 + tid] = make_float4(x, y, z, g2[k]);
    }
    __syncthreads();

    // ---- phase 1: gt-side min; scalar pred loads + packed f32 math ----
    {
        v2f gxv = {gx[0], gx[1]};
        v2f gyv = {gy[0], gy[1]};
        v2f gzv = {gz[0], gz[1]};
        v2f gminv = {3.0e38f, 3.0e38f};
        const float4* __restrict__ pp = predpack + pbase;  // uniform base
        #pragma unroll 8
        for (int j = 0; j < PRANGE; ++j) {
            const float4 p = pp[j];              // uniform -> SMEM load
            v2f dot = gxv * p.x;
            dot += gyv * p.y;                    // v_pk_fma
            dot += gzv * p.z;
            v2f t = dot * -2.0f + p.w;           // p2 - 2*dot (packed fma)
            gminv.x = fminf(gminv.x, t.x);
            gminv.y = fminf(gminv.y, t.y);
        }
        const float gm0 = gminv.x + g2[0];
        const float gm1 = gminv.y + g2[1];
        int g = gbase + tid;
        if (g < NGT)       gtpart[c * NGT + g] = gm0;
        g += 256;
        if (g < NGT)       gtpart[c * NGT + g] = gm1;
    }

    // ---- phase 2: pred-side min; 4 preds component-packed, packed f32 ----
    {
        const int grp = tid >> 3;                  // 0..31 -> preds 4g..4g+3
        const int s   = tid & 7;                   // interleaved slice
        const float4 P0 = spred[4*grp+0], P1 = spred[4*grp+1];
        const float4 P2 = spred[4*grp+2], P3 = spred[4*grp+3];
        v2f px01 = {P0.x, P1.x}, px23 = {P2.x, P3.x};
        v2f py01 = {P0.y, P1.y}, py23 = {P2.y, P3.y};
        v2f pz01 = {P0.z, P1.z}, pz23 = {P2.z, P3.z};
        v2f mn01 = {3.0e38f, 3.0e38f}, mn23 = {3.0e38f, 3.0e38f};
        #pragma unroll 4
        for (int k = 0; k < GT_TILE / 8; ++k) {
            const float4 q = sgt[k * 8 + s];       // 8 addrs -> banks 0..31
            v2f d01 = px01 * q.x; d01 += py01 * q.y; d01 += pz01 * q.z;
            v2f d23 = px23 * q.x; d23 += py23 * q.y; d23 += pz23 * q.z;
            v2f t01 = d01 * -2.0f + q.w;           // g2 - 2*dot
            v2f t23 = d23 * -2.0f + q.w;
            mn01.x = fminf(mn01.x, t01.x); mn01.y = fminf(mn01.y, t01.y);
            mn23.x = fminf(mn23.x, t23.x); mn23.y = fminf(mn23.y, t23.y);
        }
        float mn[4] = {mn01.x, mn01.y, mn23.x, mn23.y};
        float pw[4] = {P0.w, P1.w, P2.w, P3.w};
        #pragma unroll
        for (int off = 1; off < 8; off <<= 1) {
            #pragma unroll
            for (int r = 0; r < 4; ++r)
                mn[r] = fminf(mn[r], __shfl_xor(mn[r], off, 64));
        }
        if (s == 0) {
            #pragma unroll
            for (int r = 0; r < 4; ++r) {
                const int pj = 4*grp + r;
                if (pj < np)
                    atomicMin((int*)(predmin + poff + coff + pj),
                              __float_as_int(mn[r] + pw[r]));
            }
        }
    }
}

// ---------------------------------------------------------------------------
// Partial reduce + fused final (last-block pattern).
// Index space: [0,30000) gt min-combine over 27 gtpart slices |
// [30000,33240) predmin | [33240,42942) edges | [42942,46182) laplace.
// Last block (atomicAdd on counter) sums the 128 partials in fixed tree
// order -> deterministic regardless of which block finishes last.
// ---------------------------------------------------------------------------
__global__ __launch_bounds__(256) void partial_kernel(
    const float* __restrict__ pc0, const float* __restrict__ pc1, const float* __restrict__ pc2,
    const float* __restrict__ pbd0, const float* __restrict__ pbd1, const float* __restrict__ pbd2,
    const int* __restrict__ ed0, const int* __restrict__ ed1, const int* __restrict__ ed2,
    const int* __restrict__ li0, const int* __restrict__ li1, const int* __restrict__ li2,
    const float* __restrict__ gtpart, const float* __restrict__ predmin,
    float* __restrict__ partials, unsigned* __restrict__ counter,
    float* __restrict__ out)
{
    const int   NVs[3]   = {156, 618, 2466};
    const int   NEs[3]   = {462, 1848, 7392};
    const int   poffs[3] = {0, 156, 774};
    const int   eoffs[3] = {0, 462, 2310};
    const float lapc[3]  = {0.2f, 1.0f, 1.0f};
    const float* pcs[3]  = {pc0, pc1, pc2};
    const float* pbds[3] = {pbd0, pbd1, pbd2};
    const int*   eds[3]  = {ed0, ed1, ed2};
    const int*   lis[3]  = {li0, li1, li2};

    const int tid = threadIdx.x;
    const int stride = gridDim.x * 256;
    float ch = 0.f, ed = 0.f, lp = 0.f;

    for (int idx = blockIdx.x * 256 + tid; idx < 46182; idx += stride) {
        if (idx < 30000) {
            const int g = idx;
            float m0 = fminf(gtpart[0*NGT + g], gtpart[1*NGT + g]);
            float m1 = 3.0e38f;
            #pragma unroll
            for (int cc = 2; cc < 7; ++cc)  m1 = fminf(m1, gtpart[cc*NGT + g]);
            float m2 = 3.0e38f;
            #pragma unroll
            for (int cc = 7; cc < 27; ++cc) m2 = fminf(m2, gtpart[cc*NGT + g]);
            ch += (m0 + m1 + m2) * (1.0f / 30000.0f);
        } else if (idx < 33240) {
            int p = idx - 30000;
            int m = (p < 156) ? 0 : (p < 774) ? 1 : 2;
            ch += predmin[p] * (1.0f / (float)NVs[m]);
        } else if (idx < 42942) {
            int e = idx - 33240;
            int m = (e < 462) ? 0 : (e < 2310) ? 1 : 2;
            int el = e - eoffs[m];
            const int* E = eds[m];
            const float* P = pcs[m];
            int a = E[2*el], b = E[2*el+1];
            float dx = P[3*a]   - P[3*b];
            float dy = P[3*a+1] - P[3*b+1];
            float dz = P[3*a+2] - P[3*b+2];
            ed += (dx*dx + dy*dy + dz*dz) * (300.0f / (float)NEs[m]);
        } else {
            int v = idx - 42942;
            int m = (v < 156) ? 0 : (v < 774) ? 1 : 2;
            int vl = v - poffs[m];
            const int* L = lis[m];
            const float* PB = pbds[m];
            const float* PC = pcs[m];
            float mvx = PB[3*vl]   - PC[3*vl];
            float mvy = PB[3*vl+1] - PC[3*vl+1];
            float mvz = PB[3*vl+2] - PC[3*vl+2];
            float sx = 0.f, sy = 0.f, sz = 0.f;
            #pragma unroll
            for (int k = 0; k < 8; ++k) {
                int nb = L[10*vl + k];
                if (nb >= 0) {
                    sx += PB[3*nb]   - PC[3*nb];
                    sy += PB[3*nb+1] - PC[3*nb+1];
                    sz += PB[3*nb+2] - PC[3*nb+2];
                }
            }
            float invdeg = 1.0f / (float)L[10*vl + 9];
            float dx = mvx - sx * invdeg;
            float dy = mvy - sy * invdeg;
            float dz = mvz - sz * invdeg;
            float t = dx*dx + dy*dy + dz*dz;
            if (m > 0) t += mvx*mvx + mvy*mvy + mvz*mvz;
            lp += t * (lapc[m] / (float)NVs[m]);
        }
    }

    __shared__ float sred[12];
    __shared__ int is_last;
    for (int off = 32; off; off >>= 1) {
        ch += __shfl_down(ch, off, 64);
        ed += __shfl_down(ed, off, 64);
        lp += __shfl_down(lp, off, 64);
    }
    const int lane = tid & 63, wid = tid >> 6;
    if (lane == 0) { sred[wid] = ch; sred[4 + wid] = ed; sred[8 + wid] = lp; }
    __syncthreads();
    if (tid == 0) {
        partials[blockIdx.x * 4 + 0] = sred[0] + sred[1] + sred[2] + sred[3];
        partials[blockIdx.x * 4 + 1] = sred[4] + sred[5] + sred[6] + sred[7];
        partials[blockIdx.x * 4 + 2] = sred[8] + sred[9] + sred[10] + sred[11];
        __threadfence();
        unsigned prev = atomicAdd(counter, 1u);
        is_last = (prev == (unsigned)(gridDim.x - 1)) ? 1 : 0;
    }
    __syncthreads();

    if (is_last) {
        __threadfence();
        float c2 = 0.f, e2 = 0.f, l2 = 0.f;
        if (tid < RB) {
            c2 = partials[4*tid]; e2 = partials[4*tid+1]; l2 = partials[4*tid+2];
        }
        for (int off = 32; off; off >>= 1) {
            c2 += __shfl_down(c2, off, 64);
            e2 += __shfl_down(e2, off, 64);
            l2 += __shfl_down(l2, off, 64);
        }
        __shared__ float s2[12];
        if (lane == 0) { s2[wid] = c2; s2[4 + wid] = e2; s2[8 + wid] = l2; }
        __syncthreads();
        if (tid == 0) {
            float C = s2[0] + s2[1];       // wids 2,3 contributed zeros
            float E = s2[4] + s2[5];
            float L = s2[8] + s2[9];
            out[0] = 100.0f * C + 0.1f * E + 0.3f * L;
            out[1] = C;
            out[2] = E;
            out[3] = L;
        }
    }
}

extern "C" void kernel_launch(void* const* d_in, const int* in_sizes, int n_in,
                              void* d_out, int out_size, void* d_ws, size_t ws_size,
                              hipStream_t stream) {
    const float* gt   = (const float*)d_in[0];
    const float* pc0  = (const float*)d_in[1];
    const float* pbd0 = (const float*)d_in[2];
    const int*   ed0  = (const int*)  d_in[3];
    const int*   li0  = (const int*)  d_in[4];
    const float* pc1  = (const float*)d_in[5];
    const float* pbd1 = (const float*)d_in[6];
    const int*   ed1  = (const int*)  d_in[7];
    const int*   li1  = (const int*)  d_in[8];
    const float* pc2  = (const float*)d_in[9];
    const float* pbd2 = (const float*)d_in[10];
    const int*   ed2  = (const int*)  d_in[11];
    const int*   li2  = (const int*)  d_in[12];

    float* ws        = (float*)d_ws;
    float4* predpack = (float4*)(ws + OFF_PREDPACK);
    float* gtpart    = ws + OFF_GTPART;
    float* predmin   = ws + OFF_PREDMIN;
    float* partials  = ws + OFF_PARTIALS;
    unsigned* counter = (unsigned*)(ws + OFF_COUNTER);
    float* out       = (float*)d_out;

    pack_kernel<<<(NPACK + 255) / 256, 256, 0, stream>>>(
        pbd0, pbd1, pbd2, predpack, predmin, counter);

    dim3 grid(NBLK_G, NCHUNK);
    chamfer_kernel<<<grid, 256, 0, stream>>>(gt, predpack, gtpart, predmin);

    partial_kernel<<<RB, 256, 0, stream>>>(pc0, pc1, pc2, pbd0, pbd1, pbd2,
                                           ed0, ed1, ed2, li0, li1, li2,
                                           gtpart, predmin, partials, counter, out);
}